// Round 1
// baseline (897.951 us; speedup 1.0000x reference)
//
#include <hip/hip_runtime.h>
#include <hip/hip_bf16.h>
#include <cstdint>

// Problem constants
#define NUM_FIELDS 26
#define VOCAB      100000
#define BATCH      16384
#define CONCAT_K   416      // 415 (351 interactions + 64 dense_out) padded to 416
#define TOPN       256

typedef __attribute__((ext_vector_type(8)))  short bf16x8_t;
typedef __attribute__((ext_vector_type(16))) float f32x16_t;

__device__ __forceinline__ short f2bf(float x) {
  unsigned u = __builtin_bit_cast(unsigned, x);
  u += 0x7FFFu + ((u >> 16) & 1u);   // RNE; inputs finite
  return (short)(u >> 16);
}

// ---------------------------------------------------------------------------
// K0: prep. u1 = Wp@W1, c1 = bp@W1 + b1. dense_out(price) is piecewise-linear
// in the scalar price with breakpoints t_j = -c1_j/u1_j. Build sorted
// breakpoints (bps[128]) and per-segment (P,Q)[129][64] so that
// dense_out[d] = relu(price*P[seg][d] + Q[seg][d]).  Exact fp32.
// One block, 128 threads.
// ---------------------------------------------------------------------------
__global__ void k0_prepare(const float* __restrict__ Wp, const float* __restrict__ bp,
                           const float* __restrict__ W1, const float* __restrict__ b1,
                           const float* __restrict__ W2, const float* __restrict__ b2,
                           float* __restrict__ bps, float* __restrict__ PQ) {
  __shared__ float u1s[128], c1s[128], ts[128];
  __shared__ int ord[128];
  const int j = threadIdx.x;
  float u = 0.f, c = 0.f;
  for (int d = 0; d < 64; ++d) {
    float w = W1[d * 128 + j];
    u = fmaf(Wp[d], w, u);
    c = fmaf(bp[d], w, c);
  }
  c += b1[j];
  u1s[j] = u; c1s[j] = c;
  ts[j] = (u != 0.f) ? (-c / u) : __builtin_inff();  // u==0: never toggles
  __syncthreads();
  const float tj = ts[j];
  int r = 0;
  for (int i = 0; i < 128; ++i) {            // rank sort (ties by index)
    float ti = ts[i];
    if (ti < tj || (ti == tj && i < j)) ++r;
  }
  ord[r] = j;
  __syncthreads();
  bps[j] = ts[ord[j]];
  if (j < 64) {
    const int d = j;
    // base segment: price = -inf  ->  active iff u<0 (or u==0 && c>0)
    float P = 0.f, Q = b2[d];
    for (int k = 0; k < 128; ++k) {
      float uk = u1s[k];
      bool act = (uk < 0.f) || (uk == 0.f && c1s[k] > 0.f);
      if (act) {
        float w = W2[k * 64 + d];
        P = fmaf(uk, w, P);
        Q = fmaf(c1s[k], w, Q);
      }
    }
    PQ[d] = P; PQ[129 * 64 + d] = Q;
    // sweep breakpoints upward; crossing t_(k) toggles feature ord[k]
    for (int seg = 1; seg <= 128; ++seg) {
      int jk = ord[seg - 1];
      float uk = u1s[jk], ck = c1s[jk];
      float sgn = (uk > 0.f) ? 1.f : ((uk < 0.f) ? -1.f : 0.f);
      float w = W2[jk * 64 + d] * sgn;
      P = fmaf(uk, w, P);
      Q = fmaf(ck, w, Q);
      PQ[seg * 64 + d] = P;
      PQ[129 * 64 + seg * 64 + d] = Q;
    }
  }
}

// ---------------------------------------------------------------------------
// K1: per-sample features. One wave per sample (8 samples/wave sequentially).
// Gather 26 embedding rows + dense row -> LDS as bf16 (rows padded to 32,
// row stride 72 bf16 for bank spread). Gram = F F^T via 4x
// mfma_f32_32x32x16_bf16 with A-frag == B-frag. dense_out via (P,Q) table.
// Writes concat[s][416] fp32: [0..350] interactions, [351..414] dense_out,
// [415] = 0 pad.
// ---------------------------------------------------------------------------
__global__ __launch_bounds__(256) void k1_features(
    const int* __restrict__ x_cat, const float* __restrict__ price,
    const float* __restrict__ emb, const float* __restrict__ Wp,
    const float* __restrict__ bp, const float* __restrict__ bps_g,
    const float* __restrict__ PQ, float* __restrict__ concat) {
  __shared__ __align__(16) short Fb[4][32 * 72];
  __shared__ float bps_s[128];
  const int tid = threadIdx.x, lane = tid & 63, w = tid >> 6;
  if (tid < 128) bps_s[tid] = bps_g[tid];
  {   // zero MFMA pad rows 27..31 once (5 rows * 72 shorts = 180 dwords)
    int* zp = (int*)&Fb[w][27 * 72];
    for (int i = lane; i < 180; i += 64) zp[i] = 0;
  }
  __syncthreads();
  const float wp = Wp[lane], bpv = bp[lane];
  const int gw = blockIdx.x * 4 + w;           // 2048 waves total
  const int row = lane & 31, koff = (lane >> 5) * 8;
  for (int it = 0; it < 8; ++it) {
    const int s = gw * 8 + it;
    const float pr = price[s];
    #pragma unroll
    for (int f = 0; f < NUM_FIELDS; ++f) {
      int idx = x_cat[f * BATCH + s];                       // uniform -> s_load
      float v = emb[(size_t)(f * VOCAB + idx) * 64 + lane]; // 256B coalesced
      Fb[w][f * 72 + lane] = f2bf(v);
    }
    Fb[w][26 * 72 + lane] = f2bf(fmaf(pr, wp, bpv));        // dense row
    __syncthreads();
    // fragment: lane holds F[row][16*kk + koff + 0..7]; A-frag == B-frag
    bf16x8_t a0 = *(const bf16x8_t*)&Fb[w][row * 72 +  0 + koff];
    bf16x8_t a1 = *(const bf16x8_t*)&Fb[w][row * 72 + 16 + koff];
    bf16x8_t a2 = *(const bf16x8_t*)&Fb[w][row * 72 + 32 + koff];
    bf16x8_t a3 = *(const bf16x8_t*)&Fb[w][row * 72 + 48 + koff];
    f32x16_t acc = {0.f,0.f,0.f,0.f,0.f,0.f,0.f,0.f,0.f,0.f,0.f,0.f,0.f,0.f,0.f,0.f};
    acc = __builtin_amdgcn_mfma_f32_32x32x16_bf16(a0, a0, acc, 0, 0, 0);
    acc = __builtin_amdgcn_mfma_f32_32x32x16_bf16(a1, a1, acc, 0, 0, 0);
    acc = __builtin_amdgcn_mfma_f32_32x32x16_bf16(a2, a2, acc, 0, 0, 0);
    acc = __builtin_amdgcn_mfma_f32_32x32x16_bf16(a3, a3, acc, 0, 0, 0);
    // dense_out via piecewise table: seg = #{bps < price} (binary search)
    int lo = 0, hi = 128;
    while (lo < hi) { int mid = (lo + hi) >> 1; if (bps_s[mid] < pr) lo = mid + 1; else hi = mid; }
    float dv = fmaf(pr, PQ[lo * 64 + lane], PQ[129 * 64 + lo * 64 + lane]);
    dv = fmaxf(dv, 0.f);
    float* cb = concat + (size_t)s * CONCAT_K;
    cb[351 + lane] = dv;
    if (lane == 0) cb[415] = 0.f;
    // scatter upper-triangular interactions; C/D layout:
    // col = lane&31, rowd = (reg&3) + 8*(reg>>2) + 4*(lane>>5)
    const int jcol = row;
    const int rh = (lane >> 5) * 4;
    #pragma unroll
    for (int reg = 0; reg < 16; ++reg) {
      int i = (reg & 3) + 8 * (reg >> 2) + rh;
      if (i < jcol && jcol < 27) {
        int p = 26 * i - (i * (i - 1)) / 2 + (jcol - i - 1);  // triu_indices order
        cb[p] = acc[reg];
      }
    }
    __syncthreads();
  }
}

// ---------------------------------------------------------------------------
// K2: fp32 GEMM Cp[kb] = concat[:, kslice] @ Wt1[kslice, :]  (no bias/relu).
// Tiles: BM=128, BN=256(full), BK=32, K split in 2 (grid 128x2 = 256 blocks).
// 256 threads (16x16), per-thread 8Mx16N (N spread as 4x float4 at 64-stride
// to stay bank-conflict-free).
// ---------------------------------------------------------------------------
__global__ __launch_bounds__(256) void k2_gemm(const float* __restrict__ concat,
                                               const float* __restrict__ Wt1,
                                               float* __restrict__ Cp) {
  __shared__ float As[32][132];   // [k][m], pad 128->132
  __shared__ float Bs[32][264];   // [k][n], pad 256->264
  const int tid = threadIdx.x;
  const int tx = tid & 15, ty = tid >> 4;
  const int m0 = blockIdx.x * 128;
  const int kb = blockIdx.y;
  const int k0 = kb ? 224 : 0;
  const int nch = kb ? 6 : 7;          // 224 + 192 = 416
  float acc[8][16];
  #pragma unroll
  for (int i = 0; i < 8; ++i)
    #pragma unroll
    for (int n = 0; n < 16; ++n) acc[i][n] = 0.f;
  const int k4 = tid & 7, mrow = tid >> 3;
  const int kq = tid >> 6, n4 = tid & 63;
  for (int ch = 0; ch < nch; ++ch) {
    const int kc = k0 + ch * 32;
    #pragma unroll
    for (int rr = 0; rr < 4; ++rr) {   // stage A 128x32
      const int m = mrow + rr * 32;
      float4 a = *(const float4*)&concat[(size_t)(m0 + m) * CONCAT_K + kc + k4 * 4];
      As[k4 * 4 + 0][m] = a.x;
      As[k4 * 4 + 1][m] = a.y;
      As[k4 * 4 + 2][m] = a.z;
      As[k4 * 4 + 3][m] = a.w;
    }
    #pragma unroll
    for (int rr = 0; rr < 8; ++rr) {   // stage B 32x256 (row 415 -> zeros)
      const int k = rr * 4 + kq;
      float4 b = make_float4(0.f, 0.f, 0.f, 0.f);
      if (kc + k < 415) b = *(const float4*)&Wt1[(size_t)(kc + k) * 256 + n4 * 4];
      *(float4*)&Bs[k][n4 * 4] = b;
    }
    __syncthreads();
    #pragma unroll 4
    for (int k = 0; k < 32; ++k) {
      float av[8], bv[16];
      float4 a0 = *(const float4*)&As[k][ty * 8];
      float4 a1 = *(const float4*)&As[k][ty * 8 + 4];
      av[0]=a0.x; av[1]=a0.y; av[2]=a0.z; av[3]=a0.w;
      av[4]=a1.x; av[5]=a1.y; av[6]=a1.z; av[7]=a1.w;
      #pragma unroll
      for (int q = 0; q < 4; ++q) {
        float4 bq = *(const float4*)&Bs[k][q * 64 + tx * 4];
        bv[q*4+0]=bq.x; bv[q*4+1]=bq.y; bv[q*4+2]=bq.z; bv[q*4+3]=bq.w;
      }
      #pragma unroll
      for (int i = 0; i < 8; ++i)
        #pragma unroll
        for (int n = 0; n < 16; ++n)
          acc[i][n] = fmaf(av[i], bv[n], acc[i][n]);
    }
    __syncthreads();
  }
  #pragma unroll
  for (int i = 0; i < 8; ++i) {
    size_t ro = ((size_t)kb * BATCH + m0 + ty * 8 + i) * 256;
    #pragma unroll
    for (int q = 0; q < 4; ++q) {
      float4 v = make_float4(acc[i][q*4+0], acc[i][q*4+1], acc[i][q*4+2], acc[i][q*4+3]);
      *(float4*)&Cp[ro + q * 64 + tx * 4] = v;
    }
  }
}

// ---------------------------------------------------------------------------
// K3: out[s] = relu(C0[s]+C1[s]+bt1) . Wt2 + bt2.  One wave per sample.
// ---------------------------------------------------------------------------
__global__ __launch_bounds__(256) void k3_out(const float* __restrict__ Cp,
                                              const float* __restrict__ bt1,
                                              const float* __restrict__ Wt2,
                                              const float* __restrict__ bt2,
                                              float* __restrict__ out) {
  const int tid = threadIdx.x, lane = tid & 63, w = tid >> 6;
  const int s = blockIdx.x * 4 + w;
  const float4 c0 = *(const float4*)&Cp[(size_t)s * 256 + lane * 4];
  const float4 c1 = *(const float4*)&Cp[(size_t)(BATCH + s) * 256 + lane * 4];
  const float4 bb = *(const float4*)&bt1[lane * 4];
  const float4 w2 = *(const float4*)&Wt2[lane * 4];
  float sum = fmaxf(c0.x + c1.x + bb.x, 0.f) * w2.x
            + fmaxf(c0.y + c1.y + bb.y, 0.f) * w2.y
            + fmaxf(c0.z + c1.z + bb.z, 0.f) * w2.z
            + fmaxf(c0.w + c1.w + bb.w, 0.f) * w2.w;
  #pragma unroll
  for (int off = 32; off > 0; off >>= 1) sum += __shfl_down(sum, off, 64);
  if (lane == 0) out[s] = sum + bt2[0];
}

// ---------------------------------------------------------------------------
extern "C" void kernel_launch(void* const* d_in, const int* in_sizes, int n_in,
                              void* d_out, int out_size, void* d_ws, size_t ws_size,
                              hipStream_t stream) {
  const int*   x_cat = (const int*)d_in[0];
  const float* price = (const float*)d_in[1];
  const float* emb   = (const float*)d_in[2];
  const float* Wp    = (const float*)d_in[3];
  const float* bp    = (const float*)d_in[4];
  const float* W1    = (const float*)d_in[5];
  const float* b1    = (const float*)d_in[6];
  const float* W2    = (const float*)d_in[7];
  const float* b2    = (const float*)d_in[8];
  const float* Wt1   = (const float*)d_in[9];
  const float* bt1   = (const float*)d_in[10];
  const float* Wt2   = (const float*)d_in[11];
  const float* bt2   = (const float*)d_in[12];
  float* out = (float*)d_out;

  // ws layout (floats): PQ[2*129*64]=16512 | bps[128] | concat[16384*416] |
  // Cp[2*16384*256].  Total ~58.1 MB.
  float* ws     = (float*)d_ws;
  float* PQ     = ws;
  float* bps    = ws + 16512;
  float* concat = ws + 16640;
  float* Cp     = concat + (size_t)BATCH * CONCAT_K;

  k0_prepare<<<dim3(1), dim3(128), 0, stream>>>(Wp, bp, W1, b1, W2, b2, bps, PQ);
  k1_features<<<dim3(512), dim3(256), 0, stream>>>(x_cat, price, emb, Wp, bp, bps, PQ, concat);
  k2_gemm<<<dim3(128, 2), dim3(256), 0, stream>>>(concat, Wt1, Cp);
  k3_out<<<dim3(BATCH / 4), dim3(256), 0, stream>>>(Cp, bt1, Wt2, bt2, out);
}

// Round 2
// 826.086 us; speedup vs baseline: 1.0870x; 1.0870x over previous
//
#include <hip/hip_runtime.h>
#include <hip/hip_bf16.h>
#include <cstdint>

// Problem constants
#define NUM_FIELDS 26
#define VOCAB      100000
#define BATCH      16384
#define CK         416      // 415 (351 interactions + 64 dense_out) padded to 416

typedef __attribute__((ext_vector_type(8)))  short bf16x8_t;
typedef __attribute__((ext_vector_type(16))) float f32x16_t;

__device__ __forceinline__ short f2bf(float x) {
  unsigned u = __builtin_bit_cast(unsigned, x);
  u += 0x7FFFu + ((u >> 16) & 1u);   // RNE; inputs finite
  return (short)(u >> 16);
}

// ---------------------------------------------------------------------------
// K0: dense_out(price) is piecewise-linear in scalar price (<=128 breakpoints).
// Build sorted breakpoints bps[128] and per-segment (P,Q)[129][64]:
// dense_out[d] = relu(price*P[seg][d] + Q[seg][d]).  Exact fp32.
// ---------------------------------------------------------------------------
__global__ void k0_prepare(const float* __restrict__ Wp, const float* __restrict__ bp,
                           const float* __restrict__ W1, const float* __restrict__ b1,
                           const float* __restrict__ W2, const float* __restrict__ b2,
                           float* __restrict__ bps, float* __restrict__ PQ) {
  __shared__ float u1s[128], c1s[128], ts[128];
  __shared__ int ord[128];
  const int j = threadIdx.x;
  float u = 0.f, c = 0.f;
  for (int d = 0; d < 64; ++d) {
    float w = W1[d * 128 + j];
    u = fmaf(Wp[d], w, u);
    c = fmaf(bp[d], w, c);
  }
  c += b1[j];
  u1s[j] = u; c1s[j] = c;
  ts[j] = (u != 0.f) ? (-c / u) : __builtin_inff();
  __syncthreads();
  const float tj = ts[j];
  int r = 0;
  for (int i = 0; i < 128; ++i) {
    float ti = ts[i];
    if (ti < tj || (ti == tj && i < j)) ++r;
  }
  ord[r] = j;
  __syncthreads();
  bps[j] = ts[ord[j]];
  if (j < 64) {
    const int d = j;
    float P = 0.f, Q = b2[d];
    for (int k = 0; k < 128; ++k) {
      float uk = u1s[k];
      bool act = (uk < 0.f) || (uk == 0.f && c1s[k] > 0.f);
      if (act) {
        float w = W2[k * 64 + d];
        P = fmaf(uk, w, P);
        Q = fmaf(c1s[k], w, Q);
      }
    }
    PQ[d] = P; PQ[129 * 64 + d] = Q;
    for (int seg = 1; seg <= 128; ++seg) {
      int jk = ord[seg - 1];
      float uk = u1s[jk], ck = c1s[jk];
      float sgn = (uk > 0.f) ? 1.f : ((uk < 0.f) ? -1.f : 0.f);
      float w = W2[jk * 64 + d] * sgn;
      P = fmaf(uk, w, P);
      Q = fmaf(ck, w, Q);
      PQ[seg * 64 + d] = P;
      PQ[129 * 64 + seg * 64 + d] = Q;
    }
  }
}

// ---------------------------------------------------------------------------
// K0b: Wt1T[n][k] = bf16(Wt1[k][n]), k padded 415->416 with 0. 256 blocks x 64.
// Scattered reads (L2-served, 426 KB total), coalesced bf16 writes.
// ---------------------------------------------------------------------------
__global__ __launch_bounds__(64) void k0b_wt1t(const float* __restrict__ Wt1,
                                               short* __restrict__ wt1t) {
  const int n = blockIdx.x;
  for (int k = threadIdx.x; k < CK; k += 64) {
    float v = (k < 415) ? Wt1[(size_t)k * 256 + n] : 0.f;
    wt1t[(size_t)n * CK + k] = f2bf(v);
  }
}

// ---------------------------------------------------------------------------
// K1: one wave per sample. float4 gather (4 rows/instr) -> LDS bf16 (32 rows,
// stride 72 shorts). Gram = F F^T via 4x mfma_f32_32x32x16_bf16 (A==B).
// dense_out via (P,Q) table. Interactions scatter-staged in LDS, then one
// coalesced 832 B bf16 row store per sample.
// ---------------------------------------------------------------------------
__global__ __launch_bounds__(256) void k1_features(
    const int* __restrict__ x_cat, const float* __restrict__ price,
    const float* __restrict__ emb, const float* __restrict__ Wp,
    const float* __restrict__ bp, const float* __restrict__ bps_g,
    const float* __restrict__ PQ, short* __restrict__ concat) {
  __shared__ __align__(16) short Fb[4][32 * 72];
  __shared__ __align__(16) short Cs[4][CK];
  __shared__ float bps_s[128];
  const int tid = threadIdx.x, lane = tid & 63, w = tid >> 6;
  if (tid < 128) bps_s[tid] = bps_g[tid];
  {   // zero MFMA pad rows 27..31 (5 rows * 72 shorts = 180 dwords)
    int* zp = (int*)&Fb[w][27 * 72];
    for (int i = lane; i < 180; i += 64) zp[i] = 0;
  }
  const int s = blockIdx.x * 4 + w;
  const float pr = price[s];
  int idxv = 0;
  if (lane < NUM_FIELDS) idxv = x_cat[lane * BATCH + s];
  // rows 0..23: 4 rows per float4 group
  const int r16 = lane >> 4, c4 = (lane & 15) * 4;
  #pragma unroll
  for (int g = 0; g < 6; ++g) {
    const int r = g * 4 + r16;
    const int idx = __shfl(idxv, r, 64);
    const float4 v = *(const float4*)&emb[((size_t)r * VOCAB + idx) * 64 + c4];
    union { short s4[4]; uint2 u; } t;
    t.s4[0] = f2bf(v.x); t.s4[1] = f2bf(v.y); t.s4[2] = f2bf(v.z); t.s4[3] = f2bf(v.w);
    *(uint2*)&Fb[w][r * 72 + c4] = t.u;
  }
  // rows 24,25 on half wave
  {
    const int r = 24 + ((lane >> 4) & 1);
    const int idx = __shfl(idxv, r, 64);
    if (lane < 32) {
      const float4 v = *(const float4*)&emb[((size_t)r * VOCAB + idx) * 64 + c4];
      union { short s4[4]; uint2 u; } t;
      t.s4[0] = f2bf(v.x); t.s4[1] = f2bf(v.y); t.s4[2] = f2bf(v.z); t.s4[3] = f2bf(v.w);
      *(uint2*)&Fb[w][r * 72 + c4] = t.u;
    }
  }
  // row 26 = dense_embed
  Fb[w][26 * 72 + lane] = f2bf(fmaf(pr, Wp[lane], bp[lane]));
  __syncthreads();
  const int row = lane & 31, koff = (lane >> 5) * 8;
  bf16x8_t a0 = *(const bf16x8_t*)&Fb[w][row * 72 +  0 + koff];
  bf16x8_t a1 = *(const bf16x8_t*)&Fb[w][row * 72 + 16 + koff];
  bf16x8_t a2 = *(const bf16x8_t*)&Fb[w][row * 72 + 32 + koff];
  bf16x8_t a3 = *(const bf16x8_t*)&Fb[w][row * 72 + 48 + koff];
  f32x16_t acc = {0.f,0.f,0.f,0.f,0.f,0.f,0.f,0.f,0.f,0.f,0.f,0.f,0.f,0.f,0.f,0.f};
  acc = __builtin_amdgcn_mfma_f32_32x32x16_bf16(a0, a0, acc, 0, 0, 0);
  acc = __builtin_amdgcn_mfma_f32_32x32x16_bf16(a1, a1, acc, 0, 0, 0);
  acc = __builtin_amdgcn_mfma_f32_32x32x16_bf16(a2, a2, acc, 0, 0, 0);
  acc = __builtin_amdgcn_mfma_f32_32x32x16_bf16(a3, a3, acc, 0, 0, 0);
  // dense_out via piecewise table
  int lo = 0, hi = 128;
  while (lo < hi) { int mid = (lo + hi) >> 1; if (bps_s[mid] < pr) lo = mid + 1; else hi = mid; }
  float dv = fmaf(pr, PQ[lo * 64 + lane], PQ[129 * 64 + lo * 64 + lane]);
  dv = fmaxf(dv, 0.f);
  Cs[w][351 + lane] = f2bf(dv);
  if (lane == 0) Cs[w][415] = 0;
  // scatter upper-tri interactions into LDS row (bf16)
  const int jc = row, rh = (lane >> 5) * 4;
  #pragma unroll
  for (int reg = 0; reg < 16; ++reg) {
    int i = (reg & 3) + 8 * (reg >> 2) + rh;
    if (i < jc && jc < 27) {
      int p = 26 * i - (i * (i - 1)) / 2 + (jc - i - 1);
      Cs[w][p] = f2bf(acc[reg]);
    }
  }
  __syncthreads();
  // coalesced row store: 52 lanes x 16 B = 832 B
  if (lane < 52) {
    *(uint4*)&concat[(size_t)s * CK + lane * 8] = ((const uint4*)Cs[w])[lane];
  }
}

// ---------------------------------------------------------------------------
// K2: bf16 MFMA top GEMM fused with final layer.
// Block = 32 M-rows, 4 waves; wave w covers n in [w*64, w*64+64) (2 N-tiles).
// Frags straight from global (concat bf16 rows; Wt1T L2-resident).
// Epilogue: relu(t+bt1)*Wt2, reduce over n -> out[32] per block.
// ---------------------------------------------------------------------------
__global__ __launch_bounds__(256) void k2_top(const short* __restrict__ concat,
    const short* __restrict__ wt1t, const float* __restrict__ bt1,
    const float* __restrict__ Wt2, const float* __restrict__ bt2,
    float* __restrict__ out) {
  __shared__ float partial_s[4][32];
  const int tid = threadIdx.x, lane = tid & 63, w = tid >> 6;
  const int m0 = blockIdx.x * 32;
  const int row = lane & 31, kh = lane >> 5;
  const short* ap  = concat + (size_t)(m0 + row) * CK + kh * 8;
  const int nb = w * 64;
  const short* bp0 = wt1t + (size_t)(nb + row) * CK + kh * 8;
  const short* bp1 = bp0 + (size_t)32 * CK;
  f32x16_t acc0 = {0.f,0.f,0.f,0.f,0.f,0.f,0.f,0.f,0.f,0.f,0.f,0.f,0.f,0.f,0.f,0.f};
  f32x16_t acc1 = acc0;
  #pragma unroll
  for (int k0 = 0; k0 < CK; k0 += 16) {
    bf16x8_t a  = *(const bf16x8_t*)(ap + k0);
    bf16x8_t b0 = *(const bf16x8_t*)(bp0 + k0);
    bf16x8_t b1 = *(const bf16x8_t*)(bp1 + k0);
    acc0 = __builtin_amdgcn_mfma_f32_32x32x16_bf16(a, b0, acc0, 0, 0, 0);
    acc1 = __builtin_amdgcn_mfma_f32_32x32x16_bf16(a, b1, acc1, 0, 0, 0);
  }
  const int n0 = nb + row;
  const float bt1a = bt1[n0], bt1b = bt1[n0 + 32];
  const float w2a  = Wt2[n0], w2b  = Wt2[n0 + 32];
  float ps[16];
  #pragma unroll
  for (int r = 0; r < 16; ++r) {
    float v0 = fmaxf(acc0[r] + bt1a, 0.f) * w2a;
    float v1 = fmaxf(acc1[r] + bt1b, 0.f) * w2b;
    ps[r] = v0 + v1;
  }
  #pragma unroll
  for (int d = 1; d <= 16; d <<= 1) {
    #pragma unroll
    for (int r = 0; r < 16; ++r) ps[r] += __shfl_xor(ps[r], d, 64);
  }
  if (row == 0) {
    const int rh = kh * 4;
    #pragma unroll
    for (int r = 0; r < 16; ++r)
      partial_s[w][(r & 3) + 8 * (r >> 2) + rh] = ps[r];
  }
  __syncthreads();
  if (tid < 32)
    out[m0 + tid] = partial_s[0][tid] + partial_s[1][tid] +
                    partial_s[2][tid] + partial_s[3][tid] + bt2[0];
}

// ---------------------------------------------------------------------------
extern "C" void kernel_launch(void* const* d_in, const int* in_sizes, int n_in,
                              void* d_out, int out_size, void* d_ws, size_t ws_size,
                              hipStream_t stream) {
  const int*   x_cat = (const int*)d_in[0];
  const float* price = (const float*)d_in[1];
  const float* emb   = (const float*)d_in[2];
  const float* Wp    = (const float*)d_in[3];
  const float* bp    = (const float*)d_in[4];
  const float* W1    = (const float*)d_in[5];
  const float* b1    = (const float*)d_in[6];
  const float* W2    = (const float*)d_in[7];
  const float* b2    = (const float*)d_in[8];
  const float* Wt1   = (const float*)d_in[9];
  const float* bt1   = (const float*)d_in[10];
  const float* Wt2   = (const float*)d_in[11];
  const float* bt2   = (const float*)d_in[12];
  float* out = (float*)d_out;

  // ws layout: PQ[2*129*64] f32 | bps[128] f32 | concat bf16[16384][416] |
  // wt1t bf16[256][416].  ~14 MB total.
  float* ws     = (float*)d_ws;
  float* PQ     = ws;
  float* bps    = ws + 16512;
  short* concat = (short*)(ws + 16640);
  short* wt1t   = concat + (size_t)BATCH * CK;

  k0_prepare<<<dim3(1),   dim3(128), 0, stream>>>(Wp, bp, W1, b1, W2, b2, bps, PQ);
  k0b_wt1t  <<<dim3(256), dim3(64),  0, stream>>>(Wt1, wt1t);
  k1_features<<<dim3(BATCH / 4), dim3(256), 0, stream>>>(x_cat, price, emb, Wp, bp, bps, PQ, concat);
  k2_top     <<<dim3(BATCH / 32), dim3(256), 0, stream>>>(concat, wt1t, bt1, Wt2, bt2, out);
}

// Round 3
// 812.224 us; speedup vs baseline: 1.1055x; 1.0171x over previous
//
#include <hip/hip_runtime.h>
#include <hip/hip_bf16.h>
#include <cstdint>

// Problem constants
#define NUM_FIELDS 26
#define VOCAB      100000
#define BATCH      16384
#define CK         416      // 415 (351 interactions + 64 dense_out) padded to 416
#define CS_STRIDE  424      // Cs leading dim (shorts); 848 B rows, 16B-aligned

typedef __attribute__((ext_vector_type(8)))  short bf16x8_t;
typedef __attribute__((ext_vector_type(16))) float f32x16_t;

__device__ __forceinline__ short f2bf(float x) {
  unsigned u = __builtin_bit_cast(unsigned, x);
  u += 0x7FFFu + ((u >> 16) & 1u);   // RNE; inputs finite
  return (short)(u >> 16);
}

// ---------------------------------------------------------------------------
// K0: block 0 -> piecewise-linear bottom-MLP table (exact fp32):
//   dense_out[d] = relu(price*P[seg][d] + Q[seg][d]), seg from bps[128].
// blocks 1..256 -> wt1t[n][k] = bf16(Wt1[k][n]), k padded 415->416 with 0.
// ---------------------------------------------------------------------------
__global__ __launch_bounds__(128) void k0_prep(
    const float* __restrict__ Wp, const float* __restrict__ bp,
    const float* __restrict__ W1, const float* __restrict__ b1,
    const float* __restrict__ W2, const float* __restrict__ b2,
    const float* __restrict__ Wt1,
    float* __restrict__ bps, float* __restrict__ PQ, short* __restrict__ wt1t) {
  if (blockIdx.x != 0) {
    const int n = blockIdx.x - 1;
    for (int k = threadIdx.x; k < CK; k += 128) {
      float v = (k < 415) ? Wt1[(size_t)k * 256 + n] : 0.f;
      wt1t[(size_t)n * CK + k] = f2bf(v);
    }
    return;
  }
  __shared__ float u1s[128], c1s[128], ts[128];
  __shared__ int ord[128];
  const int j = threadIdx.x;
  float u = 0.f, c = 0.f;
  for (int d = 0; d < 64; ++d) {
    float w = W1[d * 128 + j];
    u = fmaf(Wp[d], w, u);
    c = fmaf(bp[d], w, c);
  }
  c += b1[j];
  u1s[j] = u; c1s[j] = c;
  ts[j] = (u != 0.f) ? (-c / u) : __builtin_inff();
  __syncthreads();
  const float tj = ts[j];
  int r = 0;
  for (int i = 0; i < 128; ++i) {
    float ti = ts[i];
    if (ti < tj || (ti == tj && i < j)) ++r;
  }
  ord[r] = j;
  __syncthreads();
  bps[j] = ts[ord[j]];
  if (j < 64) {
    const int d = j;
    float P = 0.f, Q = b2[d];
    for (int k = 0; k < 128; ++k) {
      float uk = u1s[k];
      bool act = (uk < 0.f) || (uk == 0.f && c1s[k] > 0.f);
      if (act) {
        float w = W2[k * 64 + d];
        P = fmaf(uk, w, P);
        Q = fmaf(c1s[k], w, Q);
      }
    }
    PQ[d] = P; PQ[129 * 64 + d] = Q;
    for (int seg = 1; seg <= 128; ++seg) {
      int jk = ord[seg - 1];
      float uk = u1s[jk], ck = c1s[jk];
      float sgn = (uk > 0.f) ? 1.f : ((uk < 0.f) ? -1.f : 0.f);
      float w = W2[jk * 64 + d] * sgn;
      P = fmaf(uk, w, P);
      Q = fmaf(ck, w, Q);
      PQ[seg * 64 + d] = P;
      PQ[129 * 64 + seg * 64 + d] = Q;
    }
  }
}

// ---------------------------------------------------------------------------
// K1 (fused): 512 blocks x 512 threads; 32 samples/block.
// Phase 1: wave w handles samples w*4..w*4+3 sequentially. float4 gather ->
//   Fb (bf16, 32 rows @ stride 72), gram = F F^T via 4x mfma_32x32x16_bf16
//   (A==B), dense_out via (P,Q) table; results -> LDS Cs[32][424] bf16.
//   No intra-loop barriers: Fb is wave-private, ds ops are wave-in-order.
// Phase 2: top GEMM M=32, wave w covers n-slice [w*32, w*32+32); A from LDS
//   Cs, B straight from global wt1t (L2-resident). Epilogue relu+Wt2 dot,
//   butterfly-reduce over n within wave -> partial_s[w][32].
// Phase 3: sum 8 wave partials + bt2 -> out[32].
// ---------------------------------------------------------------------------
__global__ __launch_bounds__(512, 4) void k1_fused(
    const int* __restrict__ x_cat, const float* __restrict__ price,
    const float* __restrict__ emb, const float* __restrict__ Wp,
    const float* __restrict__ bp_, const float* __restrict__ bps_g,
    const float* __restrict__ PQ, const short* __restrict__ wt1t,
    const float* __restrict__ bt1, const float* __restrict__ Wt2,
    const float* __restrict__ bt2, float* __restrict__ out) {
  __shared__ __align__(16) short Fb[8][32 * 72];
  __shared__ __align__(16) short Cs[32][CS_STRIDE];
  __shared__ float partial_s[8][32];
  __shared__ float bps_s[128];
  const int tid = threadIdx.x, lane = tid & 63, w = tid >> 6;
  if (tid < 128) bps_s[tid] = bps_g[tid];
  {   // zero MFMA pad rows 27..31 of this wave's Fb (5 rows * 72 sh = 180 dw)
    int* zp = (int*)&Fb[w][27 * 72];
    for (int i = lane; i < 180; i += 64) zp[i] = 0;
  }
  __syncthreads();   // bps_s ready for all waves
  const float wpv = Wp[lane], bpv = bp_[lane];
  const int r16 = lane >> 4, c4 = (lane & 15) * 4;
  const int row = lane & 31, kh = lane >> 5;
  const int koff = kh * 8;
  // ---- phase 1 ----
  for (int it = 0; it < 4; ++it) {
    const int sm = w * 4 + it;
    const int s = blockIdx.x * 32 + sm;
    const float pr = price[s];
    int idxv = 0;
    if (lane < NUM_FIELDS) idxv = x_cat[lane * BATCH + s];
    #pragma unroll
    for (int g = 0; g < 6; ++g) {     // rows 0..23, 4 rows per float4 pass
      const int r = g * 4 + r16;
      const int idx = __shfl(idxv, r, 64);
      const float4 v = *(const float4*)&emb[((size_t)r * VOCAB + idx) * 64 + c4];
      union { short s4[4]; uint2 u; } t;
      t.s4[0] = f2bf(v.x); t.s4[1] = f2bf(v.y); t.s4[2] = f2bf(v.z); t.s4[3] = f2bf(v.w);
      *(uint2*)&Fb[w][r * 72 + c4] = t.u;
    }
    {   // rows 24,25 on half wave
      const int r = 24 + (r16 & 1);
      const int idx = __shfl(idxv, r, 64);
      if (lane < 32) {
        const float4 v = *(const float4*)&emb[((size_t)r * VOCAB + idx) * 64 + c4];
        union { short s4[4]; uint2 u; } t;
        t.s4[0] = f2bf(v.x); t.s4[1] = f2bf(v.y); t.s4[2] = f2bf(v.z); t.s4[3] = f2bf(v.w);
        *(uint2*)&Fb[w][r * 72 + c4] = t.u;
      }
    }
    Fb[w][26 * 72 + lane] = f2bf(fmaf(pr, wpv, bpv));   // dense row
    // gram (wave-private LDS; in-order ds + compiler lgkmcnt give visibility)
    bf16x8_t a0 = *(const bf16x8_t*)&Fb[w][row * 72 +  0 + koff];
    bf16x8_t a1 = *(const bf16x8_t*)&Fb[w][row * 72 + 16 + koff];
    bf16x8_t a2 = *(const bf16x8_t*)&Fb[w][row * 72 + 32 + koff];
    bf16x8_t a3 = *(const bf16x8_t*)&Fb[w][row * 72 + 48 + koff];
    f32x16_t acc = {0.f,0.f,0.f,0.f,0.f,0.f,0.f,0.f,0.f,0.f,0.f,0.f,0.f,0.f,0.f,0.f};
    acc = __builtin_amdgcn_mfma_f32_32x32x16_bf16(a0, a0, acc, 0, 0, 0);
    acc = __builtin_amdgcn_mfma_f32_32x32x16_bf16(a1, a1, acc, 0, 0, 0);
    acc = __builtin_amdgcn_mfma_f32_32x32x16_bf16(a2, a2, acc, 0, 0, 0);
    acc = __builtin_amdgcn_mfma_f32_32x32x16_bf16(a3, a3, acc, 0, 0, 0);
    // dense_out via piecewise table
    int lo = 0, hi = 128;
    while (lo < hi) { int mid = (lo + hi) >> 1; if (bps_s[mid] < pr) lo = mid + 1; else hi = mid; }
    float dv = fmaf(pr, PQ[lo * 64 + lane], PQ[129 * 64 + lo * 64 + lane]);
    dv = fmaxf(dv, 0.f);
    Cs[sm][351 + lane] = f2bf(dv);
    if (lane == 0) Cs[sm][415] = 0;
    // scatter upper-tri interactions (C/D: col=lane&31, m=(r&3)+8*(r>>2)+4*kh)
    const int jc = row, rh = kh * 4;
    #pragma unroll
    for (int reg = 0; reg < 16; ++reg) {
      int i = (reg & 3) + 8 * (reg >> 2) + rh;
      if (i < jc && jc < 27) {
        int p = 26 * i - (i * (i - 1)) / 2 + (jc - i - 1);
        Cs[sm][p] = f2bf(acc[reg]);
      }
    }
  }
  __syncthreads();   // Cs complete
  // ---- phase 2: top GEMM, M=32 (samples), wave n-slice of 32 ----
  const int n0 = w * 32;
  const short* bp0 = wt1t + (size_t)(n0 + row) * CK + koff;
  f32x16_t tacc = {0.f,0.f,0.f,0.f,0.f,0.f,0.f,0.f,0.f,0.f,0.f,0.f,0.f,0.f,0.f,0.f};
  #pragma unroll
  for (int k0 = 0; k0 < CK; k0 += 16) {
    bf16x8_t a = *(const bf16x8_t*)&Cs[row][k0 + koff];
    bf16x8_t b = *(const bf16x8_t*)(bp0 + k0);
    tacc = __builtin_amdgcn_mfma_f32_32x32x16_bf16(a, b, tacc, 0, 0, 0);
  }
  const int n = n0 + row;
  const float bt1v = bt1[n], w2v = Wt2[n];
  float ps[16];
  #pragma unroll
  for (int r = 0; r < 16; ++r) ps[r] = fmaxf(tacc[r] + bt1v, 0.f) * w2v;
  #pragma unroll
  for (int d = 1; d <= 16; d <<= 1) {
    #pragma unroll
    for (int r = 0; r < 16; ++r) ps[r] += __shfl_xor(ps[r], d, 64);
  }
  if (row == 0) {
    #pragma unroll
    for (int r = 0; r < 16; ++r)
      partial_s[w][(r & 3) + 8 * (r >> 2) + 4 * kh] = ps[r];
  }
  __syncthreads();
  // ---- phase 3 ----
  if (tid < 32) {
    float ssum = bt2[0];
    #pragma unroll
    for (int ww = 0; ww < 8; ++ww) ssum += partial_s[ww][tid];
    out[blockIdx.x * 32 + tid] = ssum;
  }
}

// ---------------------------------------------------------------------------
extern "C" void kernel_launch(void* const* d_in, const int* in_sizes, int n_in,
                              void* d_out, int out_size, void* d_ws, size_t ws_size,
                              hipStream_t stream) {
  const int*   x_cat = (const int*)d_in[0];
  const float* price = (const float*)d_in[1];
  const float* emb   = (const float*)d_in[2];
  const float* Wp    = (const float*)d_in[3];
  const float* bp    = (const float*)d_in[4];
  const float* W1    = (const float*)d_in[5];
  const float* b1    = (const float*)d_in[6];
  const float* W2    = (const float*)d_in[7];
  const float* b2    = (const float*)d_in[8];
  const float* Wt1   = (const float*)d_in[9];
  const float* bt1   = (const float*)d_in[10];
  const float* Wt2   = (const float*)d_in[11];
  const float* bt2   = (const float*)d_in[12];
  float* out = (float*)d_out;

  // ws layout: PQ[2*129*64] f32 | bps[128] f32 | wt1t bf16[256][416]. ~280 KB.
  float* ws   = (float*)d_ws;
  float* PQ   = ws;
  float* bps  = ws + 16512;
  short* wt1t = (short*)(ws + 16640);

  k0_prep <<<dim3(257), dim3(128), 0, stream>>>(Wp, bp, W1, b1, W2, b2, Wt1, bps, PQ, wt1t);
  k1_fused<<<dim3(BATCH / 32), dim3(512), 0, stream>>>(x_cat, price, emb, Wp, bp,
                                                       bps, PQ, wt1t, bt1, Wt2, bt2, out);
}